// Round 1
// baseline (303.708 us; speedup 1.0000x reference)
//
#include <hip/hip_runtime.h>

// PairwiseMamba: N=4608 seqs, T=2048, D_INNER=4, D_STATE=8, DT_RANK=1, D_CONV=2
// Kernel 1: per-block (8 seqs), chunked two-phase:
//   phase 1: 256 threads t-parallel front-end -> LDS records
//   phase 2: 256 threads = 8 seq x 32 (d,s) states, sequential scan over chunk
// Kernel 2: feat[4608,2] -> relu(proj) -> mean over P=36 -> out[8,16,16]

#define T_LEN  2048
#define N_SEQ  4608
#define SPB    8          // sequences per block
#define TC     32         // chunk length
#define NCH    (T_LEN / TC)
#define LOG2E  1.4426950408889634f
#define LN2    0.6931471805599453f

__device__ __forceinline__ float fexp2(float x){ return __builtin_amdgcn_exp2f(x); }
__device__ __forceinline__ float frcp (float x){ return __builtin_amdgcn_rcpf(x); }
__device__ __forceinline__ float flog2(float x){ return __builtin_amdgcn_logf(x); }
__device__ __forceinline__ float silu_f(float v){ return v * frcp(1.0f + fexp2(v * -LOG2E)); }

__global__ __launch_bounds__(256, 2) void mamba_feat_kernel(
    const float* __restrict__ raw,        // [N,2,T]
    const float* __restrict__ in_proj_w,  // [8,2]
    const float* __restrict__ conv_w,     // [4,2]
    const float* __restrict__ conv_b,     // [4]
    const float* __restrict__ x_proj_w,   // [17,4]
    const float* __restrict__ dt_proj_w,  // [4,1]
    const float* __restrict__ dt_proj_b,  // [4]
    const float* __restrict__ A_log,      // [4,8]
    const float* __restrict__ D_skip,     // [4]
    const float* __restrict__ out_proj_w, // [2,4]
    float* __restrict__ feat)             // [N,2]
{
    // rec2: [seq][tt][16 pair-slots * 4 floats] = (dA, dtxB) pairs, XOR-swizzled slots
    __shared__ __attribute__((aligned(16))) float rec2[SPB * TC * 64];   // 65536 B
    // recC: [plane][seq][33]; planes 0..7 = C[s], 8..11 = g[d]
    __shared__ float recC[12 * SPB * 33];                                 // 12672 B

    const int j   = threadIdx.x;
    const int seq = j >> 5;       // 0..7   (both roles)
    const int tt  = j & 31;       // phase-1: time slot in chunk
    const int k   = j & 31;       // phase-2: state index (d*8+s)
    const int d2  = k >> 3;
    const int s2  = k & 7;

    // ---------------- weights in registers ----------------
    float wi[8][2];
#pragma unroll
    for (int r = 0; r < 8; ++r){ wi[r][0] = in_proj_w[r*2]; wi[r][1] = in_proj_w[r*2+1]; }
    float cw0[4], cw1[4], cb[4], dtw[4], dtb[4], op0[4], op1[4], op0D[4], op1D[4];
#pragma unroll
    for (int d = 0; d < 4; ++d){
        cw0[d] = conv_w[d*2]; cw1[d] = conv_w[d*2+1]; cb[d] = conv_b[d];
        dtw[d] = dt_proj_w[d]; dtb[d] = dt_proj_b[d];
        op0[d] = out_proj_w[d]; op1[d] = out_proj_w[4+d];
        float Dk = D_skip[d];
        op0D[d] = op0[d] * Dk; op1D[d] = op1[d] * Dk;
    }
    float xw[17][4];
#pragma unroll
    for (int r = 0; r < 17; ++r)
#pragma unroll
        for (int d = 0; d < 4; ++d) xw[r][d] = x_proj_w[r*4 + d];
    float A2[4][8];   // A * log2(e), A = -exp(A_log)
#pragma unroll
    for (int d = 0; d < 4; ++d)
#pragma unroll
        for (int s = 0; s < 8; ++s)
            A2[d][s] = -fexp2(A_log[d*8 + s] * LOG2E) * LOG2E;

    const int n = blockIdx.x * SPB + seq;
    const float* u0base = raw + (size_t)n * 2 * T_LEN;
    const float* u1base = u0base + T_LEN;

    // phase-2 LDS address precompute (float indices)
    const int pairc   = k >> 1;
    const int halfoff = (k & 1) * 2;
    int offA[16];
#pragma unroll
    for (int m = 0; m < 16; ++m)
        offA[m] = seq*2048 + ((pairc ^ m) << 2) + halfoff;
    const int coffC = s2*264 + seq*33;
    const int coffG = (8 + d2)*264 + seq*33;

    float h = 0.f, q = 0.f, sk0 = 0.f, sk1 = 0.f;

    for (int c = 0; c < NCH; ++c){
        // ================= phase 1: front-end for t = c*TC + tt =================
        const int t = c*TC + tt;
        const float u0 = u0base[t];
        const float u1 = u1base[t];
        float u0p = 0.f, u1p = 0.f;
        if (t > 0){ u0p = u0base[t-1]; u1p = u1base[t-1]; }

        float x[4], g[4];
#pragma unroll
        for (int d = 0; d < 4; ++d){
            float xr = fmaf(u0,  wi[d][0], u1  * wi[d][1]);
            float xp = fmaf(u0p, wi[d][0], u1p * wi[d][1]);
            float zr = fmaf(u0,  wi[4+d][0], u1 * wi[4+d][1]);
            float xc = fmaf(xp, cw0[d], fmaf(xr, cw1[d], cb[d]));
            x[d] = silu_f(xc);
            g[d] = silu_f(zr);
        }
        float dtr = 0.f;
#pragma unroll
        for (int d = 0; d < 4; ++d) dtr = fmaf(x[d], xw[0][d], dtr);
        float Bv[8], Cv[8];
#pragma unroll
        for (int s = 0; s < 8; ++s){
            float b  = x[0] * xw[1+s][0];
            float cc = x[0] * xw[9+s][0];
#pragma unroll
            for (int d = 1; d < 4; ++d){
                b  = fmaf(x[d], xw[1+s][d], b);
                cc = fmaf(x[d], xw[9+s][d], cc);
            }
            Bv[s] = b; Cv[s] = cc;
        }
        float dt[4], dtx[4];
#pragma unroll
        for (int d = 0; d < 4; ++d){
            float v = fmaf(dtr, dtw[d], dtb[d]);
            dt[d]  = LN2 * flog2(1.0f + fexp2(v * LOG2E));   // softplus
            dtx[d] = dt[d] * x[d];
        }
        // skip term: sum_d op_c[d]*D[d]*g[d]*x[d]
#pragma unroll
        for (int d = 0; d < 4; ++d){
            float gx = g[d] * x[d];
            sk0 = fmaf(gx, op0D[d], sk0);
            sk1 = fmaf(gx, op1D[d], sk1);
        }
        // write recC (conflict-spread via pitch 33 / plane stride 264)
        const int cbase = seq*33 + tt;
#pragma unroll
        for (int s = 0; s < 8; ++s) recC[s*264 + cbase] = Cv[s];
#pragma unroll
        for (int d = 0; d < 4; ++d) recC[(8+d)*264 + cbase] = g[d];
        // write rec2: (dA, dtxB) for states 2*k2, 2*k2+1 as one float4, swizzled slot
        const int rbase = seq*2048 + tt*64;
        const int ttm   = tt & 15;
#pragma unroll
        for (int k2 = 0; k2 < 16; ++k2){
            const int kk = k2 * 2;
            const int da = kk >> 3, sa = kk & 7;
            float4 v4;
            v4.x = fexp2(dt[da] * A2[da][sa]);
            v4.y = dtx[da] * Bv[sa];
            v4.z = fexp2(dt[da] * A2[da][sa+1]);
            v4.w = dtx[da] * Bv[sa+1];
            *(float4*)&rec2[rbase + ((k2 ^ ttm) << 2)] = v4;
        }
        __syncthreads();
        // ================= phase 2: scan TC steps, lane = (seq, d2, s2) =========
#pragma unroll
        for (int st = 0; st < TC; ++st){
            const int sm = st & 15;
            const float2 ab = *(const float2*)&rec2[offA[sm] + st*64];
            const float Ct = recC[coffC + st];
            const float gt = recC[coffG + st];
            h = fmaf(ab.x, h, ab.y);
            q = fmaf(h, Ct * gt, q);
        }
        __syncthreads();
    }

    // ---------------- reduce over 32-lane group ----------------
    float v0 = fmaf(q, op0[d2], sk0);
    float v1 = fmaf(q, op1[d2], sk1);
#pragma unroll
    for (int m = 16; m >= 1; m >>= 1){
        v0 += __shfl_xor(v0, m, 64);
        v1 += __shfl_xor(v1, m, 64);
    }
    if (k == 0){
        feat[(size_t)n*2    ] = v0 * (1.0f / T_LEN);
        feat[(size_t)n*2 + 1] = v1 * (1.0f / T_LEN);
    }
}

__global__ void proj_kernel(const float* __restrict__ feat,   // [N,2]
                            const float* __restrict__ pw,     // [16,2]
                            const float* __restrict__ pb,     // [16]
                            float* __restrict__ out)          // [8*16*16]
{
    const int tid = blockIdx.x * blockDim.x + threadIdx.x;    // 0..2047
    const int grp = tid >> 4;                                 // b*16+w, 0..127
    const int m   = tid & 15;
    const float w0 = pw[m*2], w1 = pw[m*2+1], b = pb[m];
    const float* f = feat + (size_t)grp * 36 * 2;
    float acc = 0.f;
#pragma unroll
    for (int p = 0; p < 36; ++p){
        float v = fmaf(f[p*2], w0, fmaf(f[p*2+1], w1, b));
        acc += fmaxf(v, 0.f);
    }
    out[tid] = acc * (1.0f / 36.0f);
}

extern "C" void kernel_launch(void* const* d_in, const int* in_sizes, int n_in,
                              void* d_out, int out_size, void* d_ws, size_t ws_size,
                              hipStream_t stream)
{
    (void)in_sizes; (void)n_in; (void)out_size; (void)ws_size;
    const float* raw        = (const float*)d_in[0];
    const float* in_proj_w  = (const float*)d_in[1];
    const float* conv_w     = (const float*)d_in[2];
    const float* conv_b     = (const float*)d_in[3];
    const float* x_proj_w   = (const float*)d_in[4];
    const float* dt_proj_w  = (const float*)d_in[5];
    const float* dt_proj_b  = (const float*)d_in[6];
    const float* A_log      = (const float*)d_in[7];
    const float* D_skip     = (const float*)d_in[8];
    const float* out_proj_w = (const float*)d_in[9];
    const float* proj_w     = (const float*)d_in[10];
    const float* proj_b     = (const float*)d_in[11];

    float* feat = (float*)d_ws;   // 4608*2 floats = 36864 B

    mamba_feat_kernel<<<dim3(N_SEQ / SPB), dim3(256), 0, stream>>>(
        raw, in_proj_w, conv_w, conv_b, x_proj_w, dt_proj_w, dt_proj_b,
        A_log, D_skip, out_proj_w, feat);

    proj_kernel<<<dim3(8), dim3(256), 0, stream>>>(feat, proj_w, proj_b, (float*)d_out);
}

// Round 2
// 161.290 us; speedup vs baseline: 1.8830x; 1.8830x over previous
//
#include <hip/hip_runtime.h>

// PairwiseMamba: N=4608 seqs, T=2048, D_INNER=4, D_STATE=8, DT_RANK=1, D_CONV=2
// R2 structure: block = 64 threads (1 wave) = 2 seqs.
//   phase 1: 2 seq x 32 t front-end -> minimal 32-float LDS record per (seq,t)
//            record: [ (dt,dtx) x4 d | (B,C) x8 s | g x4 | pad ], slots XOR-swizzled
//   phase 2: 2 seq x 32 (d,s) lanes scan the 32 steps; dA computed in-lane via exp2.
// No multi-wave barriers (syncthreads lowers to waitcnt for 1-wave blocks).
// Kernel 2: feat[4608,2] -> relu(proj) -> mean over P=36 -> out[8,16,16]

#define T_LEN  2048
#define N_SEQ  4608
#define SPB    2          // sequences per block
#define TC     32         // chunk length
#define NCH    (T_LEN / TC)
#define LOG2E  1.4426950408889634f
#define LN2    0.6931471805599453f

__device__ __forceinline__ float fexp2(float x){ return __builtin_amdgcn_exp2f(x); }
__device__ __forceinline__ float frcp (float x){ return __builtin_amdgcn_rcpf(x); }
__device__ __forceinline__ float flog2(float x){ return __builtin_amdgcn_logf(x); }
__device__ __forceinline__ float silu_f(float v){ return v * frcp(1.0f + fexp2(v * -LOG2E)); }

__global__ __launch_bounds__(64, 4) void mamba_feat_kernel(
    const float* __restrict__ raw,        // [N,2,T]
    const float* __restrict__ in_proj_w,  // [8,2]
    const float* __restrict__ conv_w,     // [4,2]
    const float* __restrict__ conv_b,     // [4]
    const float* __restrict__ x_proj_w,   // [17,4]
    const float* __restrict__ dt_proj_w,  // [4,1]
    const float* __restrict__ dt_proj_b,  // [4]
    const float* __restrict__ A_log,      // [4,8]
    const float* __restrict__ D_skip,     // [4]
    const float* __restrict__ out_proj_w, // [2,4]
    float* __restrict__ feat)             // [N,2]
{
    // rec[seq][t][32 floats]; 16B slots 0..7, slot index XOR-swizzled by (t&7)
    __shared__ __attribute__((aligned(16))) float rec[SPB * TC * 32];   // 8 KiB

    const int j   = threadIdx.x;   // 0..63
    const int seq = j >> 5;        // 0..1 (both roles)
    const int tt  = j & 31;        // phase-1: time slot in chunk
    const int d2  = (j & 31) >> 3; // phase-2: inner channel
    const int s2  = j & 7;         // phase-2: state

    // ---------------- weights in registers ----------------
    float wi[8][2];
#pragma unroll
    for (int r = 0; r < 8; ++r){ wi[r][0] = in_proj_w[r*2]; wi[r][1] = in_proj_w[r*2+1]; }
    float cw0[4], cw1[4], cb[4], dtw[4], dtb[4], op0[4], op1[4], op0D[4], op1D[4];
#pragma unroll
    for (int d = 0; d < 4; ++d){
        cw0[d] = conv_w[d*2]; cw1[d] = conv_w[d*2+1]; cb[d] = conv_b[d];
        dtw[d] = dt_proj_w[d]; dtb[d] = dt_proj_b[d];
        op0[d] = out_proj_w[d]; op1[d] = out_proj_w[4+d];
        float Dk = D_skip[d];
        op0D[d] = op0[d] * Dk; op1D[d] = op1[d] * Dk;
    }
    float xw[17][4];
#pragma unroll
    for (int r = 0; r < 17; ++r)
#pragma unroll
        for (int d = 0; d < 4; ++d) xw[r][d] = x_proj_w[r*4 + d];
    // per-lane A*log2(e) for phase 2 (generic in A_log)
    const float A2l = -fexp2(A_log[d2*8 + s2] * LOG2E) * LOG2E;

    const int n = blockIdx.x * SPB + seq;
    const float* u0base = raw + (size_t)n * 2 * T_LEN;
    const float* u1base = u0base + T_LEN;

    // phase-2 LDS float-index tables (compile-time indexed after unroll)
    const int sbase = seq * (TC * 32);
    const int sl_dt = d2 >> 1,        in_dt = (d2 & 1) * 2;
    const int sl_bc = 2 + (s2 >> 1),  in_bc = (s2 & 1) * 2;
    int odt[8], obc[8], og[8];
#pragma unroll
    for (int k2 = 0; k2 < 8; ++k2){
        odt[k2] = sbase + ((sl_dt ^ k2) << 2) + in_dt;
        obc[k2] = sbase + ((sl_bc ^ k2) << 2) + in_bc;
        og [k2] = sbase + ((6     ^ k2) << 2) + d2;
    }

    float h = 0.f, q = 0.f, sk0 = 0.f, sk1 = 0.f;

    // preload u for chunk 0
    float cu0 = u0base[tt], cu1 = u1base[tt];
    float pu0 = (tt > 0) ? u0base[tt-1] : 0.f;
    float pu1 = (tt > 0) ? u1base[tt-1] : 0.f;
    float nu0 = 0.f, nu1 = 0.f, np0 = 0.f, np1 = 0.f;

    for (int c = 0; c < NCH; ++c){
        // ================= phase 1: front-end for t = c*TC + tt =================
        float x[4], g[4];
#pragma unroll
        for (int d = 0; d < 4; ++d){
            float xr = fmaf(cu0, wi[d][0],   cu1 * wi[d][1]);
            float xp = fmaf(pu0, wi[d][0],   pu1 * wi[d][1]);
            float zr = fmaf(cu0, wi[4+d][0], cu1 * wi[4+d][1]);
            float xc = fmaf(xp, cw0[d], fmaf(xr, cw1[d], cb[d]));
            x[d] = silu_f(xc);
            g[d] = silu_f(zr);
        }
        float dtr = 0.f;
#pragma unroll
        for (int d = 0; d < 4; ++d) dtr = fmaf(x[d], xw[0][d], dtr);
        float Bv[8], Cv[8];
#pragma unroll
        for (int s = 0; s < 8; ++s){
            float b  = x[0] * xw[1+s][0];
            float cc = x[0] * xw[9+s][0];
#pragma unroll
            for (int d = 1; d < 4; ++d){
                b  = fmaf(x[d], xw[1+s][d], b);
                cc = fmaf(x[d], xw[9+s][d], cc);
            }
            Bv[s] = b; Cv[s] = cc;
        }
        float dt[4], dtx[4];
#pragma unroll
        for (int d = 0; d < 4; ++d){
            float v = fmaf(dtr, dtw[d], dtb[d]);
            dt[d]  = LN2 * flog2(1.0f + fexp2(v * LOG2E));   // softplus
            dtx[d] = dt[d] * x[d];
        }
#pragma unroll
        for (int d = 0; d < 4; ++d){
            float gx = g[d] * x[d];
            sk0 = fmaf(gx, op0D[d], sk0);
            sk1 = fmaf(gx, op1D[d], sk1);
        }
        // write the 32-float record (7 x b128, slot XOR-swizzle by tt&7)
        {
            const int rb = seq*(TC*32) + tt*32;
            const int tk = tt & 7;
            *(float4*)&rec[rb + ((0^tk)<<2)] = make_float4(dt[0], dtx[0], dt[1], dtx[1]);
            *(float4*)&rec[rb + ((1^tk)<<2)] = make_float4(dt[2], dtx[2], dt[3], dtx[3]);
            *(float4*)&rec[rb + ((2^tk)<<2)] = make_float4(Bv[0], Cv[0], Bv[1], Cv[1]);
            *(float4*)&rec[rb + ((3^tk)<<2)] = make_float4(Bv[2], Cv[2], Bv[3], Cv[3]);
            *(float4*)&rec[rb + ((4^tk)<<2)] = make_float4(Bv[4], Cv[4], Bv[5], Cv[5]);
            *(float4*)&rec[rb + ((5^tk)<<2)] = make_float4(Bv[6], Cv[6], Bv[7], Cv[7]);
            *(float4*)&rec[rb + ((6^tk)<<2)] = make_float4(g[0], g[1], g[2], g[3]);
        }
        __syncthreads();   // 1-wave block: lowers to waitcnt (+ cheap barrier)

        // prefetch u for chunk c+1 (hides HBM latency under phase 2)
        if (c + 1 < NCH){
            const int t = (c+1)*TC + tt;
            nu0 = u0base[t];   nu1 = u1base[t];
            np0 = u0base[t-1]; np1 = u1base[t-1];
        }

        // ================= phase 2: scan TC steps, lane = (seq, d2, s2) =========
#pragma unroll
        for (int st = 0; st < TC; ++st){
            const int k2 = st & 7;        // compile-time after unroll
            const int tb = st * 32;
            const float2 ddx = *(const float2*)&rec[tb + odt[k2]];  // (dt_d, dtx_d)
            const float2 bc  = *(const float2*)&rec[tb + obc[k2]];  // (B_s, C_s)
            const float  gt  = rec[tb + og[k2]];                    // g_d
            const float dA = fexp2(ddx.x * A2l);
            h = fmaf(dA, h, ddx.y * bc.x);
            q = fmaf(h, bc.y * gt, q);
        }
        __syncthreads();

        cu0 = nu0; cu1 = nu1; pu0 = np0; pu1 = np1;
    }

    // ---------------- reduce over the 32-lane seq group ----------------
    float v0 = fmaf(q, op0[d2], sk0);
    float v1 = fmaf(q, op1[d2], sk1);
#pragma unroll
    for (int m = 16; m >= 1; m >>= 1){
        v0 += __shfl_xor(v0, m, 64);
        v1 += __shfl_xor(v1, m, 64);
    }
    if ((j & 31) == 0){
        feat[(size_t)n*2    ] = v0 * (1.0f / T_LEN);
        feat[(size_t)n*2 + 1] = v1 * (1.0f / T_LEN);
    }
}

__global__ void proj_kernel(const float* __restrict__ feat,   // [N,2]
                            const float* __restrict__ pw,     // [16,2]
                            const float* __restrict__ pb,     // [16]
                            float* __restrict__ out)          // [8*16*16]
{
    const int tid = blockIdx.x * blockDim.x + threadIdx.x;    // 0..2047
    const int grp = tid >> 4;                                 // b*16+w, 0..127
    const int m   = tid & 15;
    const float w0 = pw[m*2], w1 = pw[m*2+1], b = pb[m];
    const float* f = feat + (size_t)grp * 36 * 2;
    float acc = 0.f;
#pragma unroll
    for (int p = 0; p < 36; ++p){
        float v = fmaf(f[p*2], w0, fmaf(f[p*2+1], w1, b));
        acc += fmaxf(v, 0.f);
    }
    out[tid] = acc * (1.0f / 36.0f);
}

extern "C" void kernel_launch(void* const* d_in, const int* in_sizes, int n_in,
                              void* d_out, int out_size, void* d_ws, size_t ws_size,
                              hipStream_t stream)
{
    (void)in_sizes; (void)n_in; (void)out_size; (void)ws_size;
    const float* raw        = (const float*)d_in[0];
    const float* in_proj_w  = (const float*)d_in[1];
    const float* conv_w     = (const float*)d_in[2];
    const float* conv_b     = (const float*)d_in[3];
    const float* x_proj_w   = (const float*)d_in[4];
    const float* dt_proj_w  = (const float*)d_in[5];
    const float* dt_proj_b  = (const float*)d_in[6];
    const float* A_log      = (const float*)d_in[7];
    const float* D_skip     = (const float*)d_in[8];
    const float* out_proj_w = (const float*)d_in[9];
    const float* proj_w     = (const float*)d_in[10];
    const float* proj_b     = (const float*)d_in[11];

    float* feat = (float*)d_ws;   // 4608*2 floats = 36864 B

    mamba_feat_kernel<<<dim3(N_SEQ / SPB), dim3(64), 0, stream>>>(
        raw, in_proj_w, conv_w, conv_b, x_proj_w, dt_proj_w, dt_proj_b,
        A_log, D_skip, out_proj_w, feat);

    proj_kernel<<<dim3(8), dim3(256), 0, stream>>>(feat, proj_w, proj_b, (float*)d_out);
}